// Round 12
// baseline (1581.586 us; speedup 1.0000x reference)
//
#include <hip/hip_runtime.h>
#include <hip/hip_cooperative_groups.h>
#include <stdint.h>
#include <stddef.h>

namespace cg = cooperative_groups;

#define NN 50000
#define NE 800000
#define DD 128
#define NL 4
#define NG 512
#define NC 10
#define NB 196           // buckets of 256 dest nodes
#define BCAP 5056        // per-bucket capacity (standalone p2 only)
#define GPB 49           // standalone p2 extra blocks for gptr
#define GRID 768
#define TPB 256

using short8 = __attribute__((ext_vector_type(8))) short;
using f32x4  = __attribute__((ext_vector_type(4))) float;

__device__ __forceinline__ float bf2f(unsigned short u) {
  union { unsigned int i; float f; } c; c.i = ((unsigned int)u) << 16; return c.f;
}
__device__ __forceinline__ unsigned short f2bf(float f) {
  union { unsigned int i; float f; } c; c.f = f;
  unsigned int i = c.i;
  return (unsigned short)((i + 0x7FFFu + ((i >> 16) & 1u)) >> 16);
}
__device__ __forceinline__ unsigned int pack2(float a, float b) {
  return (unsigned int)f2bf(a) | ((unsigned int)f2bf(b) << 16);
}
__device__ __forceinline__ void acc8(float* a, uint4 p) {
  a[0] += bf2f((unsigned short)(p.x & 0xffffu)); a[1] += bf2f((unsigned short)(p.x >> 16));
  a[2] += bf2f((unsigned short)(p.y & 0xffffu)); a[3] += bf2f((unsigned short)(p.y >> 16));
  a[4] += bf2f((unsigned short)(p.z & 0xffffu)); a[5] += bf2f((unsigned short)(p.z >> 16));
  a[6] += bf2f((unsigned short)(p.w & 0xffffu)); a[7] += bf2f((unsigned short)(p.w >> 16));
}

// ============ cooperative mega-kernel (GRID=768, 3 blocks/CU guaranteed) ============
__global__ __launch_bounds__(TPB, 3) void mega_k(
    const float* __restrict__ x, const int* __restrict__ erow,
    const int* __restrict__ ecol, const int* __restrict__ batch,
    const float* __restrict__ Wc, const float* __restrict__ bc,
    const float* __restrict__ W1, const float* __restrict__ b1,
    const float* __restrict__ W2, const float* __restrict__ b2,
    const float* __restrict__ W3, const float* __restrict__ b3,
    float* __restrict__ out,
    int* __restrict__ histM, int* __restrict__ cursor, int* __restrict__ ebase,
    int* __restrict__ csr_ptr, int* __restrict__ gptr, int* __restrict__ csr_src,
    float* __restrict__ dinv, unsigned short* __restrict__ Wbt,
    unsigned int* __restrict__ ebuf,
    unsigned short* __restrict__ xb, unsigned short* __restrict__ aggb,
    unsigned short* __restrict__ hA, unsigned short* __restrict__ hB)
{
  cg::grid_group grid = cg::this_grid();
  const int bid = blockIdx.x, tid = threadIdx.x;

  __shared__ int lh[256];
  __shared__ int lcnt[256], gb[256];
  __shared__ int hist_s[256], scn[256], lcur[256];
  __shared__ float dinv_s[256];
  __shared__ float s_g[128], s_h1[128], s_h2[64];

  // ---------- phase A: per-chunk bucket histogram ----------
  if (bid < NB) {
    lh[tid] = 0;
    __syncthreads();
    int e0 = bid * 4096 + tid;
#pragma unroll
    for (int j = 0; j < 16; ++j) {
      int e = e0 + j * 256;
      if (e < NE) atomicAdd(&lh[ecol[e] >> 8], 1);
    }
    __syncthreads();
    histM[bid * 256 + tid] = lh[tid];
  }
  grid.sync();

  // ---------- phase B: column-sum + scan -> ebase, cursor ----------
  if (bid == 0) {
    int h = 0;
    for (int b = 0; b < NB; ++b) h += histM[b * 256 + tid];
    lh[tid] = h;
    __syncthreads();
    for (int off = 1; off < 256; off <<= 1) {
      int v = (tid >= off) ? lh[tid - off] : 0;
      __syncthreads();
      lh[tid] += v;
      __syncthreads();
    }
    if (tid < NB) { ebase[tid] = lh[tid] - h; cursor[tid] = lh[tid] - h; }
    if (tid == NB - 1) ebase[NB] = lh[tid];
    if (tid == 0) csr_ptr[NN] = NE;
  }
  grid.sync();

  // ---------- phase C: place packed edges (4 rounds of 1024) ----------
  if (bid < NB) {
    for (int rnd = 0; rnd < 4; ++rnd) {
      if (tid < NB) lcnt[tid] = 0;
      __syncthreads();
      int bk[4], sl[4]; unsigned int pk[4];
      int e0 = bid * 4096 + rnd * 1024 + tid;
#pragma unroll
      for (int j = 0; j < 4; ++j) {
        int e = e0 + j * 256;
        bk[j] = -1;
        if (e < NE) {
          int d = ecol[e], s = erow[e];
          bk[j] = d >> 8;
          pk[j] = ((unsigned int)(d & 255) << 16) | (unsigned int)s;
          sl[j] = atomicAdd(&lcnt[bk[j]], 1);
        }
      }
      __syncthreads();
      if (tid < NB) {
        int c = lcnt[tid];
        gb[tid] = c ? atomicAdd(&cursor[tid], c) : 0;
      }
      __syncthreads();
#pragma unroll
      for (int j = 0; j < 4; ++j)
        if (bk[j] >= 0) ebuf[gb[bk[j]] + sl[j]] = pk[j];
      __syncthreads();
    }
  }
  grid.sync();

  // ---------- phase D: counting sort + dinv + x->bf16 | gptr | W transpose ----------
  if (bid < NB) {
    int beg = ebase[bid];
    int cnt = ebase[bid + 1] - beg;
    hist_s[tid] = 0;
    __syncthreads();
    for (int i = tid; i < cnt; i += TPB)
      atomicAdd(&hist_s[ebuf[beg + i] >> 16], 1);
    __syncthreads();
    scn[tid] = hist_s[tid];
    __syncthreads();
    for (int off = 1; off < 256; off <<= 1) {
      int v = (tid >= off) ? scn[tid - off] : 0;
      __syncthreads();
      scn[tid] += v;
      __syncthreads();
    }
    {
      int ex = scn[tid] - hist_s[tid];
      lcur[tid] = ex;
      int V = bid * 256 + tid;
      if (V < NN) {
        csr_ptr[V] = beg + ex;
        float dv = rsqrtf((float)(hist_s[tid] + 1));
        dinv[V] = dv;
        dinv_s[tid] = dv;
      }
    }
    __syncthreads();
    for (int i = tid; i < cnt; i += TPB) {
      unsigned int p = ebuf[beg + i];
      int pos = atomicAdd(&lcur[p >> 16], 1);
      csr_src[beg + pos] = (int)(p & 0xFFFFu);
    }
    for (int i4 = tid; i4 < 256 * 32; i4 += TPB) {
      int vl = i4 >> 5;
      int V = bid * 256 + vl;
      if (V < NN) {
        float d = dinv_s[vl];
        int q = i4 & 31;
        f32x4 vx = *((const f32x4*)(x + (size_t)V * DD) + q);
        uint2 o;
        o.x = pack2(vx[0] * d, vx[1] * d);
        o.y = pack2(vx[2] * d, vx[3] * d);
        ((uint2*)(xb + (size_t)V * DD))[q] = o;
      }
    }
  } else if (bid < NB + 196) {
    int i = (bid - NB) * 256 + tid;
    if (i < NN) {
      int bb = batch[i];
      int bp = (i == 0) ? -1 : batch[i - 1];
      for (int g = bp + 1; g <= bb; ++g) gptr[g] = i;
      if (i == NN - 1) { for (int g = bb + 1; g <= NG; ++g) gptr[g] = NN; }
    }
  } else if (bid < NB + 196 + NL) {
    int l = bid - NB - 196;
    const float* W = Wc + (size_t)l * DD * DD;
    unsigned short* WT = Wbt + (size_t)l * DD * DD;
    for (int i = tid; i < DD * DD; i += TPB) {
      int n = i >> 7, k = i & 127;
      WT[n * DD + k] = f2bf(W[k * DD + n]);
    }
  }
  grid.sync();

  // ---------- layers: (agg -> sync -> gemm -> sync) x 4 ----------
  for (int l = 0; l < NL; ++l) {
    const unsigned short* hs = (l == 0) ? xb : ((l & 1) ? hA : hB);
    unsigned short* dst = (l & 1) ? hB : hA;
    int last = (l == NL - 1);

    {  // agg (R7 body, grid-strided waves)
      int lane = tid & 63;
      int qg = lane >> 4, r = lane & 15;
      const uint4* rows = (const uint4*)hs;
      int waveId = bid * 4 + (tid >> 6);
      for (int v = waveId; v < NN; v += GRID * 4) {
        float a[8] = {0.f,0.f,0.f,0.f,0.f,0.f,0.f,0.f};
        float b[8] = {0.f,0.f,0.f,0.f,0.f,0.f,0.f,0.f};
        if (qg == 0) acc8(a, rows[(size_t)v * 16 + r]);
        int e = csr_ptr[v] + qg, end = csr_ptr[v + 1];
        for (; e + 12 < end; e += 16) {
          int s0 = csr_src[e];
          int s1 = csr_src[e + 4];
          int s2 = csr_src[e + 8];
          int s3 = csr_src[e + 12];
          uint4 p0 = rows[(size_t)s0 * 16 + r];
          uint4 p1 = rows[(size_t)s1 * 16 + r];
          uint4 p2 = rows[(size_t)s2 * 16 + r];
          uint4 p3 = rows[(size_t)s3 * 16 + r];
          acc8(a, p0); acc8(b, p1); acc8(a, p2); acc8(b, p3);
        }
        for (; e + 4 < end; e += 8) {
          int s0 = csr_src[e];
          int s1 = csr_src[e + 4];
          uint4 p0 = rows[(size_t)s0 * 16 + r];
          uint4 p1 = rows[(size_t)s1 * 16 + r];
          acc8(a, p0); acc8(b, p1);
        }
        if (e < end) acc8(a, rows[(size_t)csr_src[e] * 16 + r]);
#pragma unroll
        for (int t = 0; t < 8; ++t) a[t] += b[t];
#pragma unroll
        for (int t = 0; t < 8; ++t) {
          a[t] += __shfl_xor(a[t], 16, 64);
          a[t] += __shfl_xor(a[t], 32, 64);
        }
        if (qg == 0) {
          float dv = dinv[v];
          uint4 o;
          o.x = pack2(dv * a[0], dv * a[1]);
          o.y = pack2(dv * a[2], dv * a[3]);
          o.z = pack2(dv * a[4], dv * a[5]);
          o.w = pack2(dv * a[6], dv * a[7]);
          *((uint4*)(aggb + (size_t)v * DD) + r) = o;
        }
      }
    }
    grid.sync();

    {  // gemm: 64-row tiles, LDS-free (Wbt L2-resident)
      const unsigned short* Wb = Wbt + (size_t)l * DD * DD;
      const float* bias = bc + (size_t)l * DD;
      int wave = tid >> 6, lane = tid & 63;
      int q = lane >> 4, r = lane & 15;
      for (int tt = bid; tt < (NN + 63) / 64; tt += GRID) {
        int row0 = tt * 64 + wave * 16;
        int arow = row0 + r;
        if (arow > NN - 1) arow = NN - 1;
        const short* Arow = (const short*)aggb + (size_t)arow * DD;

        short8 afrag[4];
#pragma unroll
        for (int ks = 0; ks < 4; ++ks)
          afrag[ks] = *(const short8*)(Arow + ks * 32 + q * 8);

        f32x4 acc[8];
#pragma unroll
        for (int ct = 0; ct < 8; ++ct) acc[ct] = (f32x4){0.f, 0.f, 0.f, 0.f};

#pragma unroll
        for (int ks = 0; ks < 4; ++ks) {
#pragma unroll
          for (int ct = 0; ct < 8; ++ct) {
            short8 bfrag = *(const short8*)(Wb + (ct * 16 + r) * DD + ks * 32 + q * 8);
            acc[ct] = __builtin_amdgcn_mfma_f32_16x16x32_bf16(afrag[ks], bfrag, acc[ct], 0, 0, 0);
          }
        }

        int orow = row0 + q * 4;
        float sc[4];
#pragma unroll
        for (int reg = 0; reg < 4; ++reg) {
          int rr = orow + reg;
          sc[reg] = (!last && rr < NN) ? dinv[rr] : 1.f;
        }
#pragma unroll
        for (int ct = 0; ct < 8; ++ct) {
          int coln = ct * 16 + r;
          float bcv = bias[coln];
#pragma unroll
          for (int reg = 0; reg < 4; ++reg) {
            int rr = orow + reg;
            if (rr < NN) {
              float val = fmaxf(acc[ct][reg] + bcv, 0.f) * sc[reg];
              dst[(size_t)rr * DD + coln] = f2bf(val);
            }
          }
        }
      }
    }
    grid.sync();
  }

  // ---------- pool + MLP ----------
  if (bid < NG) {
    int g = bid, t = tid;
    if (t < 128) {
      int beg = gptr[g], end = gptr[g + 1];
      float acc = 0.f;
      for (int v = beg; v < end; ++v) acc += bf2f(hB[(size_t)v * DD + t]);
      s_g[t] = acc;
    }
    __syncthreads();
    if (t < 128) {
      float a = b1[t];
      for (int k = 0; k < 128; ++k) a += s_g[k] * W1[k * 128 + t];
      s_h1[t] = fmaxf(a, 0.f);
    }
    __syncthreads();
    if (t < 64) {
      float a = b2[t];
      for (int k = 0; k < 128; ++k) a += s_h1[k] * W2[k * 64 + t];
      s_h2[t] = fmaxf(a, 0.f);
    }
    __syncthreads();
    if (t < NC) {
      float a = b3[t];
      for (int k = 0; k < 64; ++k) a += s_h2[k] * W3[k * NC + t];
      out[g * NC + t] = a;
    }
  }
}

// ================= fallback pipeline (R10, proven 347.8 µs) =================

__global__ __launch_bounds__(1024) void p1a_k(const int* __restrict__ ecol,
                                              int* __restrict__ histM) {
  __shared__ int lh[NB];
  int tid = threadIdx.x;
  if (tid < NB) lh[tid] = 0;
  __syncthreads();
  int e0 = blockIdx.x * 4096 + tid;
#pragma unroll
  for (int j = 0; j < 4; ++j) {
    int e = e0 + j * 1024;
    if (e < NE) atomicAdd(&lh[ecol[e] >> 8], 1);
  }
  __syncthreads();
  if (tid < 256) histM[blockIdx.x * 256 + tid] = (tid < NB) ? lh[tid] : 0;
}

__global__ __launch_bounds__(256) void scanb_k(const int* __restrict__ histM,
                                               int* __restrict__ ebase,
                                               int* __restrict__ cursor,
                                               int* __restrict__ csr_ptr) {
  __shared__ int sc[256];
  int t = threadIdx.x;
  int h = 0;
  for (int b = 0; b < NB; ++b) h += histM[b * 256 + t];
  sc[t] = h; __syncthreads();
  for (int off = 1; off < 256; off <<= 1) {
    int v = (t >= off) ? sc[t - off] : 0;
    __syncthreads();
    sc[t] += v;
    __syncthreads();
  }
  if (t < NB) { ebase[t] = sc[t] - h; cursor[t] = sc[t] - h; }
  if (t == NB - 1) ebase[NB] = sc[t];
  if (t == 0) csr_ptr[NN] = NE;
}

__global__ __launch_bounds__(1024) void p1b_k(const int* __restrict__ erow,
                                              const int* __restrict__ ecol,
                                              int* __restrict__ cursor,
                                              unsigned int* __restrict__ ebuf) {
  __shared__ int lcnt[NB], gb[NB];
  int tid = threadIdx.x;
  if (tid < NB) lcnt[tid] = 0;
  __syncthreads();
  int e0 = blockIdx.x * 4096 + tid;
  int bk[4], sl[4]; unsigned int pk[4];
#pragma unroll
  for (int j = 0; j < 4; ++j) {
    int e = e0 + j * 1024;
    bk[j] = -1;
    if (e < NE) {
      int d = ecol[e], s = erow[e];
      bk[j] = d >> 8;
      pk[j] = ((unsigned int)(d & 255) << 16) | (unsigned int)s;
      sl[j] = atomicAdd(&lcnt[bk[j]], 1);
    }
  }
  __syncthreads();
  if (tid < NB) {
    int c = lcnt[tid];
    gb[tid] = c ? atomicAdd(&cursor[tid], c) : 0;
  }
  __syncthreads();
#pragma unroll
  for (int j = 0; j < 4; ++j)
    if (bk[j] >= 0) ebuf[gb[bk[j]] + sl[j]] = pk[j];
}

__global__ __launch_bounds__(1024) void p2_k(const unsigned int* __restrict__ ebuf,
                                             const int* __restrict__ ebase,
                                             const float* __restrict__ x,
                                             const int* __restrict__ batch,
                                             const float* __restrict__ Wc,
                                             int* __restrict__ csr_ptr,
                                             int* __restrict__ csr_src,
                                             float* __restrict__ dinv,
                                             unsigned short* __restrict__ xb,
                                             int* __restrict__ gptr,
                                             unsigned short* __restrict__ Wbt) {
  int b = blockIdx.x, tid = threadIdx.x;
  if (b >= NB + GPB) {
    int l = b - NB - GPB;
    const float* W = Wc + (size_t)l * DD * DD;
    unsigned short* WT = Wbt + (size_t)l * DD * DD;
    for (int i = tid; i < DD * DD; i += 1024) {
      int n = i >> 7, k = i & 127;
      WT[n * DD + k] = f2bf(W[k * DD + n]);
    }
    return;
  }
  if (b >= NB) {
    int i = (b - NB) * 1024 + tid;
    if (i >= NN) return;
    int bb = batch[i];
    int bp = (i == 0) ? -1 : batch[i - 1];
    for (int g = bp + 1; g <= bb; ++g) gptr[g] = i;
    if (i == NN - 1) { for (int g = bb + 1; g <= NG; ++g) gptr[g] = NN; }
    return;
  }

  __shared__ unsigned int pr[BCAP];
  __shared__ int srcb[BCAP];
  __shared__ int hist_s[256], scn[256], lcur[256];
  __shared__ float dinv_s[256];
  int beg = ebase[b];
  int cnt = ebase[b + 1] - beg;
  if (cnt > BCAP) cnt = BCAP;

  if (tid < 256) hist_s[tid] = 0;
  __syncthreads();
  for (int i = tid; i < cnt; i += 1024) {
    unsigned int p = ebuf[beg + i];
    pr[i] = p;
    atomicAdd(&hist_s[p >> 16], 1);
  }
  __syncthreads();
  if (tid < 256) scn[tid] = hist_s[tid];
  __syncthreads();
  for (int off = 1; off < 256; off <<= 1) {
    int v = (tid < 256 && tid >= off) ? scn[tid - off] : 0;
    __syncthreads();
    if (tid < 256) scn[tid] += v;
    __syncthreads();
  }
  if (tid < 256) {
    int ex = scn[tid] - hist_s[tid];
    lcur[tid] = ex;
    int V = b * 256 + tid;
    if (V < NN) {
      csr_ptr[V] = beg + ex;
      float dv = rsqrtf((float)(hist_s[tid] + 1));
      dinv[V] = dv;
      dinv_s[tid] = dv;
    }
  }
  __syncthreads();
  for (int i = tid; i < cnt; i += 1024) {
    unsigned int p = pr[i];
    int pos = atomicAdd(&lcur[p >> 16], 1);
    srcb[pos] = (int)(p & 0xFFFFu);
  }
  __syncthreads();
  for (int i = tid; i < cnt; i += 1024) csr_src[beg + i] = srcb[i];

  for (int i4 = tid; i4 < 256 * 32; i4 += 1024) {
    int vl = i4 >> 5;
    int V = b * 256 + vl;
    if (V < NN) {
      float d = dinv_s[vl];
      int q = i4 & 31;
      f32x4 vx = *((const f32x4*)(x + (size_t)V * DD) + q);
      uint2 o;
      o.x = pack2(vx[0] * d, vx[1] * d);
      o.y = pack2(vx[2] * d, vx[3] * d);
      ((uint2*)(xb + (size_t)V * DD))[q] = o;
    }
  }
}

__global__ __launch_bounds__(256) void agg_k(const unsigned short* __restrict__ hs,
                                             unsigned short* __restrict__ agg,
                                             const int* __restrict__ csr_ptr,
                                             const int* __restrict__ csr_src,
                                             const float* __restrict__ dinv) {
  int v = blockIdx.x * 4 + (threadIdx.x >> 6);
  if (v >= NN) return;
  int lane = threadIdx.x & 63;
  int qg = lane >> 4, r = lane & 15;
  const uint4* rows = (const uint4*)hs;

  float a[8] = {0.f, 0.f, 0.f, 0.f, 0.f, 0.f, 0.f, 0.f};
  float b[8] = {0.f, 0.f, 0.f, 0.f, 0.f, 0.f, 0.f, 0.f};
  if (qg == 0) acc8(a, rows[(size_t)v * 16 + r]);

  int e = csr_ptr[v] + qg, end = csr_ptr[v + 1];
  for (; e + 12 < end; e += 16) {
    int s0 = csr_src[e];
    int s1 = csr_src[e + 4];
    int s2 = csr_src[e + 8];
    int s3 = csr_src[e + 12];
    uint4 p0 = rows[(size_t)s0 * 16 + r];
    uint4 p1 = rows[(size_t)s1 * 16 + r];
    uint4 p2 = rows[(size_t)s2 * 16 + r];
    uint4 p3 = rows[(size_t)s3 * 16 + r];
    acc8(a, p0); acc8(b, p1); acc8(a, p2); acc8(b, p3);
  }
  for (; e + 4 < end; e += 8) {
    int s0 = csr_src[e];
    int s1 = csr_src[e + 4];
    uint4 p0 = rows[(size_t)s0 * 16 + r];
    uint4 p1 = rows[(size_t)s1 * 16 + r];
    acc8(a, p0); acc8(b, p1);
  }
  if (e < end) acc8(a, rows[(size_t)csr_src[e] * 16 + r]);

#pragma unroll
  for (int t = 0; t < 8; ++t) a[t] += b[t];
#pragma unroll
  for (int t = 0; t < 8; ++t) {
    a[t] += __shfl_xor(a[t], 16, 64);
    a[t] += __shfl_xor(a[t], 32, 64);
  }

  if (qg == 0) {
    float dv = dinv[v];
    uint4 o;
    o.x = pack2(dv * a[0], dv * a[1]);
    o.y = pack2(dv * a[2], dv * a[3]);
    o.z = pack2(dv * a[4], dv * a[5]);
    o.w = pack2(dv * a[6], dv * a[7]);
    *((uint4*)(agg + (size_t)v * DD) + r) = o;
  }
}

__global__ __launch_bounds__(256) void gemm_relu_k(const unsigned short* __restrict__ A,
                                                   const unsigned short* __restrict__ Wb,
                                                   const float* __restrict__ bias,
                                                   unsigned short* __restrict__ out,
                                                   const float* __restrict__ dscale,
                                                   int M) {
  __shared__ unsigned short Wt[128][136];
  int tid = threadIdx.x;
  for (int i = tid; i < 128 * 16; i += 256) {
    int rr = i >> 4, c = i & 15;
    *(uint4*)&Wt[rr][c * 8] = *(const uint4*)(Wb + rr * DD + c * 8);
  }
  __syncthreads();

  int wave = tid >> 6, lane = tid & 63;
  int q = lane >> 4, r = lane & 15;
  int row0 = blockIdx.x * 64 + wave * 16;

  int arow = row0 + r;
  if (arow > M - 1) arow = M - 1;
  const short* Arow = (const short*)A + (size_t)arow * DD;

  short8 afrag[4];
#pragma unroll
  for (int ks = 0; ks < 4; ++ks)
    afrag[ks] = *(const short8*)(Arow + ks * 32 + q * 8);

  f32x4 acc[8];
#pragma unroll
  for (int ct = 0; ct < 8; ++ct) acc[ct] = (f32x4){0.f, 0.f, 0.f, 0.f};

#pragma unroll
  for (int ks = 0; ks < 4; ++ks) {
#pragma unroll
    for (int ct = 0; ct < 8; ++ct) {
      short8 bfrag = *(const short8*)(&Wt[ct * 16 + r][ks * 32 + q * 8]);
      acc[ct] = __builtin_amdgcn_mfma_f32_16x16x32_bf16(afrag[ks], bfrag, acc[ct], 0, 0, 0);
    }
  }

  int orow = row0 + q * 4;
  float sc[4];
#pragma unroll
  for (int reg = 0; reg < 4; ++reg) {
    int rr = orow + reg;
    sc[reg] = (dscale && rr < M) ? dscale[rr] : 1.f;
  }
#pragma unroll
  for (int ct = 0; ct < 8; ++ct) {
    int coln = ct * 16 + r;
    float bc = bias[coln];
#pragma unroll
    for (int reg = 0; reg < 4; ++reg) {
      int rr = orow + reg;
      if (rr < M) {
        float val = fmaxf(acc[ct][reg] + bc, 0.f) * sc[reg];
        out[(size_t)rr * DD + coln] = f2bf(val);
      }
    }
  }
}

__global__ __launch_bounds__(128) void poolmlp_k(const unsigned short* __restrict__ h,
                                                 const int* __restrict__ gptr,
                                                 const float* __restrict__ W1,
                                                 const float* __restrict__ b1,
                                                 const float* __restrict__ W2,
                                                 const float* __restrict__ b2,
                                                 const float* __restrict__ W3,
                                                 const float* __restrict__ b3,
                                                 float* __restrict__ out) {
  __shared__ float s_g[128], s_h1[128], s_h2[64];
  int g = blockIdx.x, t = threadIdx.x;
  int beg = gptr[g], end = gptr[g + 1];
  float acc = 0.f;
  for (int v = beg; v < end; ++v) acc += bf2f(h[(size_t)v * DD + t]);
  s_g[t] = acc;
  __syncthreads();
  {
    float a = b1[t];
    for (int k = 0; k < 128; ++k) a += s_g[k] * W1[k * 128 + t];
    s_h1[t] = fmaxf(a, 0.f);
  }
  __syncthreads();
  if (t < 64) {
    float a = b2[t];
    for (int k = 0; k < 128; ++k) a += s_h1[k] * W2[k * 64 + t];
    s_h2[t] = fmaxf(a, 0.f);
  }
  __syncthreads();
  if (t < NC) {
    float a = b3[t];
    for (int k = 0; k < 64; ++k) a += s_h2[k] * W3[k * NC + t];
    out[g * NC + t] = a;
  }
}

// ---------------- launch ----------------

extern "C" void kernel_launch(void* const* d_in, const int* in_sizes, int n_in,
                              void* d_out, int out_size, void* d_ws, size_t ws_size,
                              hipStream_t stream) {
  const float* x     = (const float*)d_in[0];
  const int*   ei    = (const int*)d_in[1];
  const int*   batch = (const int*)d_in[2];
  const float* Wc    = (const float*)d_in[3];
  const float* bc    = (const float*)d_in[4];
  const float* W1    = (const float*)d_in[5];
  const float* b1    = (const float*)d_in[6];
  const float* W2    = (const float*)d_in[7];
  const float* b2    = (const float*)d_in[8];
  const float* W3    = (const float*)d_in[9];
  const float* b3    = (const float*)d_in[10];
  float* out = (float*)d_out;

  const int* erow = ei;
  const int* ecol = ei + NE;

  char* w = (char*)d_ws;
  int*   histM   = (int*)w;    w += (size_t)NB * 256 * 4;
  int*   cursor  = (int*)w;    w += NB * 4;
  int*   ebase   = (int*)w;    w += (NB + 4) * 4;
  int*   csr_ptr = (int*)w;    w += (size_t)(NN + 4) * 4;
  int*   gptr    = (int*)w;    w += (NG + 4) * 4;
  int*   csr_src = (int*)w;    w += (size_t)NE * 4;
  float* dinv    = (float*)w;  w += (size_t)NN * 4;
  w = (char*)(((uintptr_t)w + 255) & ~(uintptr_t)255);
  unsigned short* Wbt  = (unsigned short*)w; w += (size_t)NL * DD * DD * 2;
  unsigned short* xb   = (unsigned short*)w; w += (size_t)NN * DD * 2;
  unsigned short* aggb = (unsigned short*)w; w += (size_t)NN * DD * 2;
  unsigned short* hA   = (unsigned short*)w; w += (size_t)NN * DD * 2;
  unsigned short* hB   = (unsigned short*)w; w += (size_t)NN * DD * 2;
  unsigned int* ebuf = (unsigned int*)aggb;

  void* args[] = {
    (void*)&x, (void*)&erow, (void*)&ecol, (void*)&batch,
    (void*)&Wc, (void*)&bc, (void*)&W1, (void*)&b1, (void*)&W2, (void*)&b2,
    (void*)&W3, (void*)&b3, (void*)&out,
    (void*)&histM, (void*)&cursor, (void*)&ebase, (void*)&csr_ptr, (void*)&gptr,
    (void*)&csr_src, (void*)&dinv, (void*)&Wbt, (void*)&ebuf,
    (void*)&xb, (void*)&aggb, (void*)&hA, (void*)&hB
  };
  hipError_t err = hipLaunchCooperativeKernel((void*)mega_k, dim3(GRID), dim3(TPB),
                                              args, 0, stream);
  if (err != hipSuccess) {
    // deterministic fallback: proven R10 pipeline
    p1a_k  <<<NB, 1024, 0, stream>>>(ecol, histM);
    scanb_k<<<1, 256, 0, stream>>>(histM, ebase, cursor, csr_ptr);
    p1b_k  <<<NB, 1024, 0, stream>>>(erow, ecol, cursor, ebuf);
    p2_k   <<<NB + GPB + NL, 1024, 0, stream>>>(ebuf, ebase, x, batch, Wc, csr_ptr,
                                                csr_src, dinv, xb, gptr, Wbt);
    const int aggGrid  = (NN + 3) / 4;
    const int gemmGrid = (NN + 63) / 64;
    for (int l = 0; l < NL; ++l) {
      const unsigned short* hin = (l == 0) ? xb : ((l & 1) ? hA : hB);
      unsigned short* dst = (l & 1) ? hB : hA;
      const float* dsc = (l == NL - 1) ? nullptr : dinv;
      agg_k<<<aggGrid, 256, 0, stream>>>(hin, aggb, csr_ptr, csr_src, dinv);
      gemm_relu_k<<<gemmGrid, 256, 0, stream>>>(aggb, Wbt + (size_t)l * DD * DD,
                                                bc + (size_t)l * DD, dst, dsc, NN);
    }
    poolmlp_k<<<NG, 128, 0, stream>>>(hB, gptr, W1, b1, W2, b2, W3, b3, out);
  }

  (void)in_sizes; (void)n_in; (void)out_size; (void)ws_size;
}

// Round 13
// 323.049 us; speedup vs baseline: 4.8958x; 4.8958x over previous
//
#include <hip/hip_runtime.h>
#include <stdint.h>
#include <stddef.h>

#define NN 50000
#define NE 800000
#define DD 128
#define NL 4
#define NG 512
#define NC 10
#define NB 196           // buckets of 256 dest nodes: ceil(50000/256)
#define BCAP 5056        // fixed per-bucket region capacity (mean 4081, huge margin)
#define GPB 49           // p2 extra blocks for gptr: ceil(50000/1024)

using short8 = __attribute__((ext_vector_type(8))) short;
using f32x4  = __attribute__((ext_vector_type(4))) float;

__device__ __forceinline__ float bf2f(unsigned short u) {
  union { unsigned int i; float f; } c; c.i = ((unsigned int)u) << 16; return c.f;
}
__device__ __forceinline__ unsigned short f2bf(float f) {
  union { unsigned int i; float f; } c; c.f = f;
  unsigned int i = c.i;
  return (unsigned short)((i + 0x7FFFu + ((i >> 16) & 1u)) >> 16);
}
__device__ __forceinline__ unsigned int pack2(float a, float b) {
  return (unsigned int)f2bf(a) | ((unsigned int)f2bf(b) << 16);
}
__device__ __forceinline__ void acc8(float* a, uint4 p) {
  a[0] += bf2f((unsigned short)(p.x & 0xffffu)); a[1] += bf2f((unsigned short)(p.x >> 16));
  a[2] += bf2f((unsigned short)(p.y & 0xffffu)); a[3] += bf2f((unsigned short)(p.y >> 16));
  a[4] += bf2f((unsigned short)(p.z & 0xffffu)); a[5] += bf2f((unsigned short)(p.z >> 16));
  a[6] += bf2f((unsigned short)(p.w & 0xffffu)); a[7] += bf2f((unsigned short)(p.w >> 16));
}

// ---------------- p1b: place packed edges into FIXED bucket regions ----------------
// No histogram/scan pass needed: region base = b*BCAP, slot via atomic cursor.
__global__ __launch_bounds__(1024) void p1b_k(const int* __restrict__ erow,
                                              const int* __restrict__ ecol,
                                              int* __restrict__ cursor,
                                              unsigned int* __restrict__ ebuf) {
  __shared__ int lcnt[NB], gb[NB];
  int tid = threadIdx.x;
  if (tid < NB) lcnt[tid] = 0;
  __syncthreads();
  int e0 = blockIdx.x * 4096 + tid;
  int bk[4], sl[4]; unsigned int pk[4];
#pragma unroll
  for (int j = 0; j < 4; ++j) {
    int e = e0 + j * 1024;
    bk[j] = -1;
    if (e < NE) {
      int d = ecol[e], s = erow[e];
      bk[j] = d >> 8;
      pk[j] = ((unsigned int)(d & 255) << 16) | (unsigned int)s;
      sl[j] = atomicAdd(&lcnt[bk[j]], 1);
    }
  }
  __syncthreads();
  if (tid < NB) {
    int c = lcnt[tid];
    gb[tid] = c ? atomicAdd(&cursor[tid], c) : 0;
  }
  __syncthreads();
#pragma unroll
  for (int j = 0; j < 4; ++j)
    if (bk[j] >= 0) ebuf[(size_t)bk[j] * BCAP + gb[bk[j]] + sl[j]] = pk[j];
}

// ---------------- p2: bucket counting sort + dinv + x->bf16*dinv | gptr | W transpose ----
// blocks [0,NB): bucket work (count from cursor[b], base b*BCAP);
// [NB,NB+GPB): gptr; [NB+GPB,NB+GPB+NL): Wc -> Wbt (bf16, transposed)
__global__ __launch_bounds__(1024) void p2_k(const unsigned int* __restrict__ ebuf,
                                             const int* __restrict__ cursor,
                                             const float* __restrict__ x,
                                             const int* __restrict__ batch,
                                             const float* __restrict__ Wc,
                                             int* __restrict__ csr_ptr,
                                             int* __restrict__ csr_end,
                                             int* __restrict__ csr_src,
                                             float* __restrict__ dinv,
                                             unsigned short* __restrict__ xb,
                                             int* __restrict__ gptr,
                                             unsigned short* __restrict__ Wbt) {
  int b = blockIdx.x, tid = threadIdx.x;
  if (b >= NB + GPB) {                   // W conversion role
    int l = b - NB - GPB;
    const float* W = Wc + (size_t)l * DD * DD;
    unsigned short* WT = Wbt + (size_t)l * DD * DD;
    for (int i = tid; i < DD * DD; i += 1024) {
      int n = i >> 7, k = i & 127;
      WT[n * DD + k] = f2bf(W[k * DD + n]);
    }
    return;
  }
  if (b >= NB) {                         // gptr role
    int i = (b - NB) * 1024 + tid;
    if (i >= NN) return;
    int bb = batch[i];
    int bp = (i == 0) ? -1 : batch[i - 1];
    for (int g = bp + 1; g <= bb; ++g) gptr[g] = i;
    if (i == NN - 1) { for (int g = bb + 1; g <= NG; ++g) gptr[g] = NN; }
    return;
  }

  __shared__ unsigned int pr[BCAP];
  __shared__ int srcb[BCAP];
  __shared__ int hist_s[256], scn[256], lcur[256];
  __shared__ float dinv_s[256];
  size_t beg = (size_t)b * BCAP;
  int cnt = cursor[b];
  if (cnt > BCAP) cnt = BCAP;            // safety (never hit)

  if (tid < 256) hist_s[tid] = 0;
  __syncthreads();
  for (int i = tid; i < cnt; i += 1024) {
    unsigned int p = ebuf[beg + i];
    pr[i] = p;
    atomicAdd(&hist_s[p >> 16], 1);
  }
  __syncthreads();
  if (tid < 256) scn[tid] = hist_s[tid];
  __syncthreads();
  for (int off = 1; off < 256; off <<= 1) {
    int v = (tid < 256 && tid >= off) ? scn[tid - off] : 0;
    __syncthreads();
    if (tid < 256) scn[tid] += v;
    __syncthreads();
  }
  if (tid < 256) {
    int ex = scn[tid] - hist_s[tid];
    lcur[tid] = ex;
    int V = b * 256 + tid;
    if (V < NN) {
      csr_ptr[V] = (int)beg + ex;
      csr_end[V] = (int)beg + scn[tid];
      float dv = rsqrtf((float)(hist_s[tid] + 1));
      dinv[V] = dv;
      dinv_s[tid] = dv;
    }
  }
  __syncthreads();
  for (int i = tid; i < cnt; i += 1024) {
    unsigned int p = pr[i];
    int pos = atomicAdd(&lcur[p >> 16], 1);
    srcb[pos] = (int)(p & 0xFFFFu);
  }
  __syncthreads();
  for (int i = tid; i < cnt; i += 1024) csr_src[beg + i] = srcb[i];

  // x -> bf16 pre-scaled by dinv (row-major)
  for (int i4 = tid; i4 < 256 * 32; i4 += 1024) {
    int vl = i4 >> 5;
    int V = b * 256 + vl;
    if (V < NN) {
      float d = dinv_s[vl];
      int q = i4 & 31;
      f32x4 vx = *((const f32x4*)(x + (size_t)V * DD) + q);
      uint2 o;
      o.x = pack2(vx[0] * d, vx[1] * d);
      o.y = pack2(vx[2] * d, vx[3] * d);
      ((uint2*)(xb + (size_t)V * DD))[q] = o;
    }
  }
}

// ---------------- aggregation (R7 proven body; explicit begin/end) ----------------
__global__ __launch_bounds__(256) void agg_k(const unsigned short* __restrict__ hs,
                                             unsigned short* __restrict__ agg,
                                             const int* __restrict__ csr_ptr,
                                             const int* __restrict__ csr_end,
                                             const int* __restrict__ csr_src,
                                             const float* __restrict__ dinv) {
  int v = blockIdx.x * 4 + (threadIdx.x >> 6);
  if (v >= NN) return;
  int lane = threadIdx.x & 63;
  int qg = lane >> 4, r = lane & 15;
  const uint4* rows = (const uint4*)hs;   // row v = rows[v*16 + r]

  float a[8] = {0.f, 0.f, 0.f, 0.f, 0.f, 0.f, 0.f, 0.f};
  float b[8] = {0.f, 0.f, 0.f, 0.f, 0.f, 0.f, 0.f, 0.f};
  if (qg == 0) acc8(a, rows[(size_t)v * 16 + r]);   // self term

  int e = csr_ptr[v] + qg, end = csr_end[v];
  for (; e + 12 < end; e += 16) {
    int s0 = csr_src[e];
    int s1 = csr_src[e + 4];
    int s2 = csr_src[e + 8];
    int s3 = csr_src[e + 12];
    uint4 p0 = rows[(size_t)s0 * 16 + r];
    uint4 p1 = rows[(size_t)s1 * 16 + r];
    uint4 p2 = rows[(size_t)s2 * 16 + r];
    uint4 p3 = rows[(size_t)s3 * 16 + r];
    acc8(a, p0); acc8(b, p1); acc8(a, p2); acc8(b, p3);
  }
  for (; e + 4 < end; e += 8) {
    int s0 = csr_src[e];
    int s1 = csr_src[e + 4];
    uint4 p0 = rows[(size_t)s0 * 16 + r];
    uint4 p1 = rows[(size_t)s1 * 16 + r];
    acc8(a, p0); acc8(b, p1);
  }
  if (e < end) acc8(a, rows[(size_t)csr_src[e] * 16 + r]);

#pragma unroll
  for (int t = 0; t < 8; ++t) a[t] += b[t];
#pragma unroll
  for (int t = 0; t < 8; ++t) {
    a[t] += __shfl_xor(a[t], 16, 64);
    a[t] += __shfl_xor(a[t], 32, 64);
  }

  if (qg == 0) {
    float dv = dinv[v];
    uint4 o;
    o.x = pack2(dv * a[0], dv * a[1]);
    o.y = pack2(dv * a[2], dv * a[3]);
    o.z = pack2(dv * a[4], dv * a[5]);
    o.w = pack2(dv * a[6], dv * a[7]);
    *((uint4*)(agg + (size_t)v * DD) + r) = o;
  }
}

// ---------------- fused GEMM: out = relu(A @ W + b) [* dinv], bf16 in/out ----------------
__global__ __launch_bounds__(256) void gemm_relu_k(const unsigned short* __restrict__ A,
                                                   const unsigned short* __restrict__ Wb,
                                                   const float* __restrict__ bias,
                                                   unsigned short* __restrict__ out,
                                                   const float* __restrict__ dscale,
                                                   int M) {
  __shared__ unsigned short Wt[128][136];   // [n][k] bf16, +8 pad
  int tid = threadIdx.x;
  for (int i = tid; i < 128 * 16; i += 256) {
    int rr = i >> 4, c = i & 15;
    *(uint4*)&Wt[rr][c * 8] = *(const uint4*)(Wb + rr * DD + c * 8);
  }
  __syncthreads();

  int wave = tid >> 6, lane = tid & 63;
  int q = lane >> 4, r = lane & 15;
  int row0 = blockIdx.x * 64 + wave * 16;

  int arow = row0 + r;
  if (arow > M - 1) arow = M - 1;
  const short* Arow = (const short*)A + (size_t)arow * DD;

  short8 afrag[4];
#pragma unroll
  for (int ks = 0; ks < 4; ++ks)
    afrag[ks] = *(const short8*)(Arow + ks * 32 + q * 8);

  f32x4 acc[8];
#pragma unroll
  for (int ct = 0; ct < 8; ++ct) acc[ct] = (f32x4){0.f, 0.f, 0.f, 0.f};

#pragma unroll
  for (int ks = 0; ks < 4; ++ks) {
#pragma unroll
    for (int ct = 0; ct < 8; ++ct) {
      short8 bfrag = *(const short8*)(&Wt[ct * 16 + r][ks * 32 + q * 8]);
      acc[ct] = __builtin_amdgcn_mfma_f32_16x16x32_bf16(afrag[ks], bfrag, acc[ct], 0, 0, 0);
    }
  }

  int orow = row0 + q * 4;
  float sc[4];
#pragma unroll
  for (int reg = 0; reg < 4; ++reg) {
    int rr = orow + reg;
    sc[reg] = (dscale && rr < M) ? dscale[rr] : 1.f;
  }
#pragma unroll
  for (int ct = 0; ct < 8; ++ct) {
    int coln = ct * 16 + r;
    float bc = bias[coln];
#pragma unroll
    for (int reg = 0; reg < 4; ++reg) {
      int rr = orow + reg;
      if (rr < M) {
        float val = fmaxf(acc[ct][reg] + bc, 0.f) * sc[reg];
        out[(size_t)rr * DD + coln] = f2bf(val);
      }
    }
  }
}

// ---------------- fused pool + MLP head ----------------
__global__ __launch_bounds__(128) void poolmlp_k(const unsigned short* __restrict__ h,
                                                 const int* __restrict__ gptr,
                                                 const float* __restrict__ W1,
                                                 const float* __restrict__ b1,
                                                 const float* __restrict__ W2,
                                                 const float* __restrict__ b2,
                                                 const float* __restrict__ W3,
                                                 const float* __restrict__ b3,
                                                 float* __restrict__ out) {
  __shared__ float s_g[128], s_h1[128], s_h2[64];
  int g = blockIdx.x, t = threadIdx.x;
  int beg = gptr[g], end = gptr[g + 1];
  float acc = 0.f;
  for (int v = beg; v < end; ++v) acc += bf2f(h[(size_t)v * DD + t]);
  s_g[t] = acc;
  __syncthreads();
  {
    float a = b1[t];
    for (int k = 0; k < 128; ++k) a += s_g[k] * W1[k * 128 + t];
    s_h1[t] = fmaxf(a, 0.f);
  }
  __syncthreads();
  if (t < 64) {
    float a = b2[t];
    for (int k = 0; k < 128; ++k) a += s_h1[k] * W2[k * 64 + t];
    s_h2[t] = fmaxf(a, 0.f);
  }
  __syncthreads();
  if (t < NC) {
    float a = b3[t];
    for (int k = 0; k < 64; ++k) a += s_h2[k] * W3[k * NC + t];
    out[g * NC + t] = a;
  }
}

// ---------------- launch ----------------

extern "C" void kernel_launch(void* const* d_in, const int* in_sizes, int n_in,
                              void* d_out, int out_size, void* d_ws, size_t ws_size,
                              hipStream_t stream) {
  const float* x     = (const float*)d_in[0];
  const int*   ei    = (const int*)d_in[1];
  const int*   batch = (const int*)d_in[2];
  const float* Wc    = (const float*)d_in[3];
  const float* bc    = (const float*)d_in[4];
  const float* W1    = (const float*)d_in[5];
  const float* b1    = (const float*)d_in[6];
  const float* W2    = (const float*)d_in[7];
  const float* b2    = (const float*)d_in[8];
  const float* W3    = (const float*)d_in[9];
  const float* b3    = (const float*)d_in[10];
  float* out = (float*)d_out;

  const int* erow = ei;        // edge_index[0] (source)
  const int* ecol = ei + NE;   // edge_index[1] (dest)

  char* w = (char*)d_ws;
  int*   cursor  = (int*)w;    w += NB * 4;                 // memset 0 (784 B)
  int*   csr_ptr = (int*)w;    w += (size_t)(NN + 4) * 4;
  int*   csr_end = (int*)w;    w += (size_t)(NN + 4) * 4;
  int*   gptr    = (int*)w;    w += (NG + 4) * 4;
  int*   csr_src = (int*)w;    w += (size_t)NB * BCAP * 4;  // fixed-base regions
  float* dinv    = (float*)w;  w += (size_t)NN * 4;
  w = (char*)(((uintptr_t)w + 255) & ~(uintptr_t)255);
  unsigned short* Wbt  = (unsigned short*)w; w += (size_t)NL * DD * DD * 2;
  unsigned short* xb   = (unsigned short*)w; w += (size_t)NN * DD * 2;
  unsigned short* aggb = (unsigned short*)w; w += (size_t)NN * DD * 2;
  unsigned short* hA   = (unsigned short*)w; w += (size_t)NN * DD * 2;
  unsigned short* hB   = (unsigned short*)w; w += (size_t)NN * DD * 2;
  unsigned int* ebuf = (unsigned int*)hA;    // alias: 196*BCAP*4 = 3.96MB < 12.8MB;
                                             // dead before gemm layer-0 writes hA

  hipMemsetAsync(cursor, 0, NB * 4, stream);

  p1b_k<<<NB, 1024, 0, stream>>>(erow, ecol, cursor, ebuf);
  p2_k <<<NB + GPB + NL, 1024, 0, stream>>>(ebuf, cursor, x, batch, Wc, csr_ptr,
                                            csr_end, csr_src, dinv, xb, gptr, Wbt);

  const int aggGrid  = (NN + 3) / 4;
  const int gemmGrid = (NN + 63) / 64;

  for (int l = 0; l < NL; ++l) {
    const unsigned short* hin = (l == 0) ? xb : ((l & 1) ? hA : hB);
    unsigned short* dst = (l & 1) ? hB : hA;
    const float* dsc = (l == NL - 1) ? nullptr : dinv;
    agg_k<<<aggGrid, 256, 0, stream>>>(hin, aggb, csr_ptr, csr_end, csr_src, dinv);
    gemm_relu_k<<<gemmGrid, 256, 0, stream>>>(aggb, Wbt + (size_t)l * DD * DD,
                                              bc + (size_t)l * DD, dst, dsc, NN);
  }

  poolmlp_k<<<NG, 128, 0, stream>>>(hB, gptr, W1, b1, W2, b2, W3, b3, out);

  (void)in_sizes; (void)n_in; (void)out_size; (void)ws_size;
}